// Round 5
// baseline (324.193 us; speedup 1.0000x reference)
//
#include <hip/hip_runtime.h>
#include <hip/hip_bf16.h>
#include <math.h>

typedef _Float16 half8 __attribute__((ext_vector_type(8)));
typedef _Float16 half4v __attribute__((ext_vector_type(4)));
typedef float f32x4 __attribute__((ext_vector_type(4)));

#define NB 8
#define NAA 20
#define ND 16
#define NL 512
#define NC2 4096
#define NC 2048
#define NF 12
#define NR 96      // B*F rows
#define NK 1024    // 2*L contraction for conv GEMM
#define CT 128     // c-tile (conv GEMM N-tile)
#define KC 64      // staged K-chunk (conv GEMM)
#define LSTR 72    // LDS row stride in halves (part 1)
#define CTS 136    // convT LDS stride (halves): 272B = 17*16B, rows spread banks
#define BST2 268   // part-2 A0 stage stride (halves): kg-groups 2-way only
#define NCT 16     // number of c-tiles = partial count

// ---------- Kernel A: G[d][r][j] = sum_n conv_w[f][n][k] * aa[b][n][d*L+s]
// j = k*512 + s so that G row matches Adj_d = adjs[d] reinterpreted [2048][1024].
__global__ __launch_bounds__(256) void k_g(const float* __restrict__ aa,
                                           const float* __restrict__ conv_w,
                                           _Float16* __restrict__ G) {
  int idx = blockIdx.x * 256 + threadIdx.x;   // 16*96*1024 total
  int j  = idx & (NK - 1);
  int rd = idx >> 10;
  int r  = rd % NR;
  int d  = rd / NR;
  int k  = j >> 9;
  int s  = j & (NL - 1);
  int b  = r / NF;
  int f  = r % NF;
  const float* aap = aa + (size_t)(b * NAA) * (ND * NL) + d * NL + s;
  const float* wp  = conv_w + f * NAA * 2 + k;
  float acc = 0.f;
#pragma unroll
  for (int n = 0; n < NAA; ++n)
    acc += wp[n * 2] * aap[(size_t)n * (ND * NL)];
  G[idx] = (_Float16)acc;
}

// ---------- Fused: conv GEMM (part 1, = proven k_conv) then contract GEMM
// (part 2) against the block's own 128 even adj rows (L3-hot re-read).
// Output: one fp16 partial aa2p[ct][d][96][512] per block. No conv round-trip,
// no second adjs HBM pass, no atomics on aa2.
__global__ __launch_bounds__(256) void k_fused(const float* __restrict__ adjs,
                                               const _Float16* __restrict__ G,
                                               _Float16* __restrict__ aa2p,
                                               float* __restrict__ deg) {
  __shared__ _Float16 lA[NR * LSTR];
  __shared__ _Float16 lB[CT * LSTR];
  __shared__ float degp[16][16][4];
  __shared__ _Float16 convT[NR * CTS];
  __shared__ _Float16 lB2[32 * BST2];

  int bid = blockIdx.x;                     // 256 blocks
  int d  = ((bid & 7) << 1) | ((bid >> 3) & 1);  // d-pair pinned per XCD slot
  int ct = bid >> 4;                        // 0..15
  int t = threadIdx.x;
  int w = t >> 6;
  int lane = t & 63;
  int l16 = lane & 15;
  int kg  = lane >> 4;
  int c0 = ct * CT;
  const float*    Adj = adjs + (size_t)d * NC2 * NL;   // as [2048][1024] row-major
  const _Float16* Gd  = G + (size_t)d * NR * NK;

  // ---------------- part 1: conv tile [96 x 128] ----------------
  f32x4 acc[6][2];
#pragma unroll
  for (int i = 0; i < 6; ++i)
#pragma unroll
    for (int q = 0; q < 2; ++q) acc[i][q] = (f32x4)0.f;

  int brow0 = t >> 4;       // 0..15
  int col4  = t & 15;       // 0..15

  for (int kc = 0; kc < NK / KC; ++kc) {
#pragma unroll
    for (int i = 0; i < 3; ++i) {
      int q = i * 256 + t;
      int row = q >> 3;
      int c8  = q & 7;
      uint4 v = *(const uint4*)(Gd + (size_t)row * NK + kc * KC + c8 * 8);
      *(uint4*)(&lA[row * LSTR + c8 * 8]) = v;
    }
    float cs0 = 0, cs1 = 0, cs2 = 0, cs3 = 0;
#pragma unroll
    for (int i = 0; i < 8; ++i) {
      int row = brow0 + i * 16;
      const float4 v = *(const float4*)(Adj + (size_t)(c0 + row) * NK + kc * KC + col4 * 4);
      cs0 += v.x; cs1 += v.y; cs2 += v.z; cs3 += v.w;
      half4v hv = {(_Float16)v.x, (_Float16)v.y, (_Float16)v.z, (_Float16)v.w};
      *(half4v*)(&lB[row * LSTR + col4 * 4]) = hv;
    }
    degp[col4][brow0][0] = cs0;
    degp[col4][brow0][1] = cs1;
    degp[col4][brow0][2] = cs2;
    degp[col4][brow0][3] = cs3;
    __syncthreads();
    if (t < 64) {
      int cg = t >> 2, ci = t & 3;
      float sum = 0.f;
#pragma unroll
      for (int p = 0; p < 16; ++p) sum += degp[cg][p][ci];
      int j = kc * KC + cg * 4 + ci;
      int s = j & (NL - 1);
      atomicAdd(deg + d * NL + s, sum);
    }
#pragma unroll
    for (int ks = 0; ks < 2; ++ks) {
      int ko = ks * 32 + 8 * kg;
      half8 b0 = *(const half8*)(&lB[(w * 32 + l16) * LSTR + ko]);
      half8 b1 = *(const half8*)(&lB[(w * 32 + 16 + l16) * LSTR + ko]);
#pragma unroll
      for (int mf = 0; mf < 6; ++mf) {
        half8 a = *(const half8*)(&lA[(mf * 16 + l16) * LSTR + ko]);
        acc[mf][0] = __builtin_amdgcn_mfma_f32_16x16x32_f16(a, b0, acc[mf][0], 0, 0, 0);
        acc[mf][1] = __builtin_amdgcn_mfma_f32_16x16x32_f16(a, b1, acc[mf][1], 0, 0, 0);
      }
    }
    __syncthreads();
  }
  // conv tile -> LDS (c-contiguous rows for part-2 A-fragments)
  int nbase = w * 32;
#pragma unroll
  for (int mf = 0; mf < 6; ++mf)
#pragma unroll
    for (int nf = 0; nf < 2; ++nf)
#pragma unroll
      for (int jj = 0; jj < 4; ++jj) {
        int m  = mf * 16 + kg * 4 + jj;
        int cl = nbase + nf * 16 + l16;
        convT[m * CTS + cl] = (_Float16)acc[mf][nf][jj];
      }
  __syncthreads();

  // ---------------- part 2: aa2 partial [96 x 512] over 128 c ----------------
  int scl   = t >> 3;          // staged c row 0..31
  int lbase = (t & 7) * 32;    // 0..224
  for (int lh = 0; lh < 2; ++lh) {
    f32x4 acc2[6][4];
#pragma unroll
    for (int i = 0; i < 6; ++i)
#pragma unroll
      for (int q = 0; q < 4; ++q) acc2[i][q] = (f32x4)0.f;

    for (int cc2 = 0; cc2 < 4; ++cc2) {
      // stage A0 chunk [32 c][256 l] fp32->fp16 (even adj rows, L3-hot)
      const float* src = Adj + (size_t)(2 * (c0 + cc2 * 32 + scl)) * NL + lh * 256 + lbase;
#pragma unroll
      for (int q = 0; q < 8; ++q) {
        const float4 v = *(const float4*)(src + q * 4);
        half4v hv = {(_Float16)v.x, (_Float16)v.y, (_Float16)v.z, (_Float16)v.w};
        *(half4v*)(&lB2[scl * BST2 + lbase + q * 4]) = hv;
      }
      __syncthreads();
      half8 bfr[4];
#pragma unroll
      for (int nf = 0; nf < 4; ++nf) {
        int lcol = w * 64 + nf * 16 + l16;
#pragma unroll
        for (int j = 0; j < 8; ++j)
          bfr[nf][j] = lB2[(kg * 8 + j) * BST2 + lcol];
      }
#pragma unroll
      for (int mf = 0; mf < 6; ++mf) {
        half8 a = *(const half8*)(&convT[(mf * 16 + l16) * CTS + cc2 * 32 + kg * 8]);
#pragma unroll
        for (int nf = 0; nf < 4; ++nf)
          acc2[mf][nf] = __builtin_amdgcn_mfma_f32_16x16x32_f16(a, bfr[nf], acc2[mf][nf], 0, 0, 0);
      }
      __syncthreads();
    }
    _Float16* outp = aa2p + (size_t)(ct * ND + d) * NR * NL;
#pragma unroll
    for (int mf = 0; mf < 6; ++mf)
#pragma unroll
      for (int nf = 0; nf < 4; ++nf)
#pragma unroll
        for (int jj = 0; jj < 4; ++jj) {
          int m = mf * 16 + kg * 4 + jj;
          int l = lh * 256 + w * 64 + nf * 16 + l16;
          outp[(size_t)m * NL + l] = (_Float16)acc2[mf][nf][jj];
        }
  }
}

// ---------- Final: sum 16 fp16 partials -> /deg -> max_l -> dot -> sigmoid
__global__ __launch_bounds__(256) void k_final(const _Float16* __restrict__ aa2p,
                                               const float* __restrict__ deg,
                                               const float* __restrict__ lin_w,
                                               float* __restrict__ out) {
  __shared__ float partw[4];
  int t = threadIdx.x;
  int w = t >> 6, lane = t & 63;
  int d = blockIdx.x >> 3, b = blockIdx.x & 7;
  float inv[8];
#pragma unroll
  for (int i = 0; i < 8; ++i)
    inv[i] = 1.0f / deg[d * NL + lane + i * 64];
  float part = 0.f;
#pragma unroll
  for (int q = 0; q < 3; ++q) {
    int f = w * 3 + q;                       // 4 waves x 3 filters = 12
    int m = b * NF + f;
    float mx = -1e30f;
#pragma unroll
    for (int i = 0; i < 8; ++i) {
      int l = lane + i * 64;
      float s = 0.f;
#pragma unroll
      for (int ct = 0; ct < NCT; ++ct)
        s += (float)aa2p[((size_t)(ct * ND + d) * NR + m) * NL + l];
      mx = fmaxf(mx, s * inv[i]);
    }
#pragma unroll
    for (int off = 32; off >= 1; off >>= 1)
      mx = fmaxf(mx, __shfl_xor(mx, off));
    part += mx * lin_w[f];
  }
  if (lane == 0) partw[w] = part;
  __syncthreads();
  if (t == 0) {
    float s = partw[0] + partw[1] + partw[2] + partw[3];
    out[d * NB + b] = 1.f / (1.f + expf(-s));
  }
}

extern "C" void kernel_launch(void* const* d_in, const int* in_sizes, int n_in,
                              void* d_out, int out_size, void* d_ws, size_t ws_size,
                              hipStream_t stream) {
  const float* aa     = (const float*)d_in[0];
  const float* adjs   = (const float*)d_in[1];
  const float* conv_w = (const float*)d_in[2];
  const float* lin_w  = (const float*)d_in[3];
  float* out = (float*)d_out;

  char* ws = (char*)d_ws;
  _Float16* G    = (_Float16*)ws;                       // 3,145,728 B
  _Float16* aa2p = (_Float16*)(ws + 3145728);           // 16 fp16 partials: 25,165,824 B
  float*    deg  = (float*)(ws + 3145728 + 25165824);   // 32 KB

  hipMemsetAsync(deg, 0, ND * NL * sizeof(float), stream);

  k_g<<<dim3((ND * NR * NK) / 256), 256, 0, stream>>>(aa, conv_w, G);
  k_fused<<<dim3(256), 256, 0, stream>>>(adjs, G, aa2p, deg);
  k_final<<<dim3(ND * NB), 256, 0, stream>>>(aa2p, deg, lin_w, out);
}

// Round 9
// 253.193 us; speedup vs baseline: 1.2804x; 1.2804x over previous
//
#include <hip/hip_runtime.h>
#include <hip/hip_bf16.h>
#include <math.h>

typedef _Float16 half8 __attribute__((ext_vector_type(8)));
typedef _Float16 half4v __attribute__((ext_vector_type(4)));
typedef float f32x4 __attribute__((ext_vector_type(4)));

#define NB 8
#define NAA 20
#define ND 16
#define NL 512
#define NC2 4096
#define NC 2048
#define NF 12
#define NR 96      // B*F rows
#define NK 1024    // 2*L contraction for conv GEMM
#define CT 128     // c-tile (conv GEMM N-tile)
#define KC 64      // staged K-chunk (conv GEMM)
#define LSTR 72    // LDS row stride in halves (part 1)
#define CTS 136    // convT LDS stride (halves)
#define BST2 514   // part-2 A0 stage stride (halves): frag gather spans 32 banks
#define NCT 16     // number of c-tiles = partial count

// ---------- Kernel A: G[d][r][j] = sum_n conv_w[f][n][k] * aa[b][n][d*L+s]
__global__ __launch_bounds__(256) void k_g(const float* __restrict__ aa,
                                           const float* __restrict__ conv_w,
                                           _Float16* __restrict__ G) {
  int idx = blockIdx.x * 256 + threadIdx.x;   // 16*96*1024 total
  int j  = idx & (NK - 1);
  int rd = idx >> 10;
  int r  = rd % NR;
  int d  = rd / NR;
  int k  = j >> 9;
  int s  = j & (NL - 1);
  int b  = r / NF;
  int f  = r % NF;
  const float* aap = aa + (size_t)(b * NAA) * (ND * NL) + d * NL + s;
  const float* wp  = conv_w + f * NAA * 2 + k;
  float acc = 0.f;
#pragma unroll
  for (int n = 0; n < NAA; ++n)
    acc += wp[n * 2] * aap[(size_t)n * (ND * NL)];
  G[idx] = (_Float16)acc;
}

// ---------- Fused conv+contract, 512 threads (8 waves/CU vs 4 in R5).
// Part 1: conv tile [96 x 128] (each wave a 96x16 c-slice).
// Part 2: partial aa2[96 x 512] over this tile's 128 c (each wave 64 l).
__global__ __launch_bounds__(512) void k_fused(const float* __restrict__ adjs,
                                               const _Float16* __restrict__ G,
                                               _Float16* __restrict__ aa2p,
                                               float* __restrict__ deg) {
  __shared__ union {
    struct { _Float16 lA[NR * LSTR]; _Float16 lB[CT * LSTR]; float degp[16][33][4]; } p1;
    struct { _Float16 convT[NR * CTS]; _Float16 lB2[32 * BST2]; } p2;
  } S;

  int bid = blockIdx.x;                     // 256 blocks
  int d  = ((bid & 7) << 1) | ((bid >> 3) & 1);  // d-pair pinned per XCD slot
  int ct = bid >> 4;                        // 0..15
  int t = threadIdx.x;                      // 0..511
  int w = t >> 6;                           // 0..7
  int lane = t & 63;
  int l16 = lane & 15;
  int kg  = lane >> 4;
  int c0 = ct * CT;
  const float*    Adj = adjs + (size_t)d * NC2 * NL;   // as [2048][1024] row-major
  const _Float16* Gd  = G + (size_t)d * NR * NK;

  // ---------------- part 1: conv tile [96 x 128] ----------------
  f32x4 acc[6];
#pragma unroll
  for (int i = 0; i < 6; ++i) acc[i] = (f32x4)0.f;

  int brow = t >> 4;        // 0..31
  int col4 = t & 15;        // 0..15

  for (int kc = 0; kc < NK / KC; ++kc) {
    // stage A: 96 x 64 halves; 1536 uint2-units / 512 thr = 3 each
#pragma unroll
    for (int i = 0; i < 3; ++i) {
      int unit = i * 512 + t;
      int row = unit >> 4;        // 0..95
      int u   = unit & 15;        // 4-half units
      *(uint2*)(&S.p1.lA[row * LSTR + u * 4]) =
          *(const uint2*)(Gd + (size_t)row * NK + kc * KC + u * 4);
    }
    // stage B (fp32->fp16) + deg column partials: 2048 float4-units / 512 = 4
    float cs0 = 0, cs1 = 0, cs2 = 0, cs3 = 0;
#pragma unroll
    for (int i = 0; i < 4; ++i) {
      int row = i * 32 + brow;    // 0..127
      const float4 v = *(const float4*)(Adj + (size_t)(c0 + row) * NK + kc * KC + col4 * 4);
      cs0 += v.x; cs1 += v.y; cs2 += v.z; cs3 += v.w;
      half4v hv = {(_Float16)v.x, (_Float16)v.y, (_Float16)v.z, (_Float16)v.w};
      *(half4v*)(&S.p1.lB[row * LSTR + col4 * 4]) = hv;
    }
    S.p1.degp[col4][brow][0] = cs0;
    S.p1.degp[col4][brow][1] = cs1;
    S.p1.degp[col4][brow][2] = cs2;
    S.p1.degp[col4][brow][3] = cs3;
    __syncthreads();
    if (t < 64) {
      int cg = t >> 2, ci = t & 3;
      float sum = 0.f;
#pragma unroll
      for (int p = 0; p < 32; ++p) sum += S.p1.degp[cg][p][ci];
      int j = kc * KC + cg * 4 + ci;
      atomicAdd(deg + d * NL + (j & (NL - 1)), sum);
    }
#pragma unroll
    for (int ks = 0; ks < 2; ++ks) {
      int ko = ks * 32 + 8 * kg;
      half8 b0 = *(const half8*)(&S.p1.lB[(w * 16 + l16) * LSTR + ko]);
#pragma unroll
      for (int mf = 0; mf < 6; ++mf) {
        half8 a = *(const half8*)(&S.p1.lA[(mf * 16 + l16) * LSTR + ko]);
        acc[mf] = __builtin_amdgcn_mfma_f32_16x16x32_f16(a, b0, acc[mf], 0, 0, 0);
      }
    }
    __syncthreads();
  }
  // conv tile -> LDS (c-contiguous rows for part-2 A-fragments)
#pragma unroll
  for (int mf = 0; mf < 6; ++mf)
#pragma unroll
    for (int jj = 0; jj < 4; ++jj) {
      int m  = mf * 16 + kg * 4 + jj;
      S.p2.convT[m * CTS + w * 16 + l16] = (_Float16)acc[mf][jj];
    }
  __syncthreads();

  // ---------------- part 2: aa2 partial [96 x 512] over 128 c ----------------
  f32x4 acc2[6][4];
#pragma unroll
  for (int i = 0; i < 6; ++i)
#pragma unroll
    for (int q = 0; q < 4; ++q) acc2[i][q] = (f32x4)0.f;

  for (int cc2 = 0; cc2 < 4; ++cc2) {
    // stage A0 chunk [32 c][512 l] fp32->fp16: 4096 float4-units / 512 = 8
#pragma unroll
    for (int i = 0; i < 8; ++i) {
      int unit = i * 512 + t;
      int c  = unit >> 7;         // 0..31
      int l4 = unit & 127;
      const float4 v = *(const float4*)(Adj + (size_t)(2 * (c0 + cc2 * 32 + c)) * NL + l4 * 4);
      half4v hv = {(_Float16)v.x, (_Float16)v.y, (_Float16)v.z, (_Float16)v.w};
      *(half4v*)(&S.p2.lB2[c * BST2 + l4 * 4]) = hv;
    }
    __syncthreads();
    half8 bfr[4];
#pragma unroll
    for (int nf = 0; nf < 4; ++nf) {
      int lcol = w * 64 + nf * 16 + l16;
#pragma unroll
      for (int j = 0; j < 8; ++j)
        bfr[nf][j] = S.p2.lB2[(kg * 8 + j) * BST2 + lcol];
    }
#pragma unroll
    for (int mf = 0; mf < 6; ++mf) {
      half8 a = *(const half8*)(&S.p2.convT[(mf * 16 + l16) * CTS + cc2 * 32 + kg * 8]);
#pragma unroll
      for (int nf = 0; nf < 4; ++nf)
        acc2[mf][nf] = __builtin_amdgcn_mfma_f32_16x16x32_f16(a, bfr[nf], acc2[mf][nf], 0, 0, 0);
    }
    __syncthreads();
  }
  _Float16* outp = aa2p + (size_t)(ct * ND + d) * NR * NL;
#pragma unroll
  for (int mf = 0; mf < 6; ++mf)
#pragma unroll
    for (int nf = 0; nf < 4; ++nf)
#pragma unroll
      for (int jj = 0; jj < 4; ++jj) {
        int m = mf * 16 + kg * 4 + jj;
        int l = w * 64 + nf * 16 + l16;
        outp[(size_t)m * NL + l] = (_Float16)acc2[mf][nf][jj];
      }
}

// ---------- Reduce: one block per (d, r): sum 16 partials, /deg, max over l
__global__ __launch_bounds__(256) void k_reduce(const _Float16* __restrict__ aa2p,
                                                const float* __restrict__ deg,
                                                float* __restrict__ dmax) {
  __shared__ float wm[4];
  int r = blockIdx.x;         // 0..95
  int d = blockIdx.y;         // 0..15
  int t = threadIdx.x;
  int w = t >> 6, lane = t & 63;
  float best = -1e30f;
#pragma unroll
  for (int rep = 0; rep < 2; ++rep) {
    int l = t + rep * 256;
    float s = 0.f;
#pragma unroll
    for (int ct = 0; ct < NCT; ++ct)
      s += (float)aa2p[((size_t)(ct * ND + d) * NR + r) * NL + l];
    best = fmaxf(best, s / deg[d * NL + l]);
  }
#pragma unroll
  for (int off = 32; off >= 1; off >>= 1)
    best = fmaxf(best, __shfl_xor(best, off));
  if (lane == 0) wm[w] = best;
  __syncthreads();
  if (t == 0)
    dmax[d * NR + r] = fmaxf(fmaxf(wm[0], wm[1]), fmaxf(wm[2], wm[3]));
}

// ---------- Out: 128 scores = dot(dmax row, lin_w) -> sigmoid
__global__ __launch_bounds__(128) void k_out(const float* __restrict__ dmax,
                                             const float* __restrict__ lin_w,
                                             float* __restrict__ out) {
  int t = threadIdx.x;        // 0..127: d = t>>3, b = t&7
  int d = t >> 3, b = t & 7;
  float s = 0.f;
#pragma unroll
  for (int f = 0; f < NF; ++f)
    s += dmax[d * NR + b * NF + f] * lin_w[f];
  out[d * NB + b] = 1.f / (1.f + expf(-s));
}

extern "C" void kernel_launch(void* const* d_in, const int* in_sizes, int n_in,
                              void* d_out, int out_size, void* d_ws, size_t ws_size,
                              hipStream_t stream) {
  const float* aa     = (const float*)d_in[0];
  const float* adjs   = (const float*)d_in[1];
  const float* conv_w = (const float*)d_in[2];
  const float* lin_w  = (const float*)d_in[3];
  float* out = (float*)d_out;

  char* ws = (char*)d_ws;
  _Float16* G    = (_Float16*)ws;                       // 3,145,728 B
  _Float16* aa2p = (_Float16*)(ws + 3145728);           // 16 fp16 partials: 25,165,824 B
  float*    deg  = (float*)(ws + 3145728 + 25165824);   // 32 KB
  float*    dmax = (float*)(ws + 3145728 + 25165824 + 32768); // 6 KB

  hipMemsetAsync(deg, 0, ND * NL * sizeof(float), stream);

  k_g<<<dim3((ND * NR * NK) / 256), 256, 0, stream>>>(aa, conv_w, G);
  k_fused<<<dim3(256), 512, 0, stream>>>(adjs, G, aa2p, deg);
  k_reduce<<<dim3(NR, ND), 256, 0, stream>>>(aa2p, deg, dmax);
  k_out<<<dim3(1), 128, 0, stream>>>(dmax, lin_w, out);
}

// Round 11
// 246.746 us; speedup vs baseline: 1.3139x; 1.0261x over previous
//
#include <hip/hip_runtime.h>
#include <hip/hip_bf16.h>
#include <math.h>

typedef _Float16 half8 __attribute__((ext_vector_type(8)));
typedef _Float16 half4v __attribute__((ext_vector_type(4)));
typedef float f32x4 __attribute__((ext_vector_type(4)));

#define NB 8
#define NAA 20
#define ND 16
#define NL 512
#define NC2 4096
#define NC 2048
#define NF 12
#define NR 96      // B*F rows
#define NK 1024    // 2*L contraction for conv GEMM
#define CT 128     // c-tile (conv GEMM N-tile)
#define KC 64      // staged K-chunk (conv GEMM)
#define LSTR 72    // LDS row stride in halves (part 1)
#define CTS 136    // convT LDS stride (halves)
#define BST2 514   // part-2 A0 stage stride (halves): frag gather spans 32 banks
#define NCT 16     // number of c-tiles = partial count

// Raw-barrier fence: compiler memory fence + per-wave LDS drain + hw barrier.
// NO vmcnt drain -> prefetched global loads stay in flight across it (T3/T14).
#define FENCE_BARRIER()                                       \
  do {                                                        \
    asm volatile("s_waitcnt lgkmcnt(0)" ::: "memory");        \
    __builtin_amdgcn_sched_barrier(0);                        \
    __builtin_amdgcn_s_barrier();                             \
    __builtin_amdgcn_sched_barrier(0);                        \
  } while (0)

// ---------- Kernel A: G[d][r][j] = sum_n conv_w[f][n][k] * aa[b][n][d*L+s]
__global__ __launch_bounds__(256) void k_g(const float* __restrict__ aa,
                                           const float* __restrict__ conv_w,
                                           _Float16* __restrict__ G) {
  int idx = blockIdx.x * 256 + threadIdx.x;   // 16*96*1024 total
  int j  = idx & (NK - 1);
  int rd = idx >> 10;
  int r  = rd % NR;
  int d  = rd / NR;
  int k  = j >> 9;
  int s  = j & (NL - 1);
  int b  = r / NF;
  int f  = r % NF;
  const float* aap = aa + (size_t)(b * NAA) * (ND * NL) + d * NL + s;
  const float* wp  = conv_w + f * NAA * 2 + k;
  float acc = 0.f;
#pragma unroll
  for (int n = 0; n < NAA; ++n)
    acc += wp[n * 2] * aap[(size_t)n * (ND * NL)];
  G[idx] = (_Float16)acc;
}

// ---------- Fused conv+contract, 512 threads, reg-staged prefetch across
// raw barriers (no vmcnt(0) drain). Part 1: conv tile [96 x 128].
// Part 2: partial aa2[96 x 512] over this tile's 128 c.
__global__ __launch_bounds__(512) void k_fused(const float* __restrict__ adjs,
                                               const _Float16* __restrict__ G,
                                               _Float16* __restrict__ aa2p,
                                               float* __restrict__ deg) {
  __shared__ union {
    struct { _Float16 lA[NR * LSTR]; _Float16 lB[CT * LSTR]; float degp[4][16][33]; } p1;
    struct { _Float16 convT[NR * CTS]; _Float16 lB2[32 * BST2]; } p2;
  } S;

  int bid = blockIdx.x;                     // 256 blocks
  int d  = ((bid & 7) << 1) | ((bid >> 3) & 1);  // d-pair pinned per XCD slot
  int ct = bid >> 4;                        // 0..15
  int t = threadIdx.x;                      // 0..511
  int w = t >> 6;                           // 0..7
  int lane = t & 63;
  int l16 = lane & 15;
  int kg  = lane >> 4;
  int c0 = ct * CT;
  const float*    Adj = adjs + (size_t)d * NC2 * NL;   // as [2048][1024] row-major
  const _Float16* Gd  = G + (size_t)d * NR * NK;

  // ---------------- part 1: conv tile [96 x 128] ----------------
  f32x4 acc[6];
#pragma unroll
  for (int i = 0; i < 6; ++i) acc[i] = (f32x4)0.f;

  int brow = t >> 4;        // 0..31
  int col4 = t & 15;        // 0..15

  uint2  pa[3];             // prefetched A (G) regs
  float4 pb[4];             // prefetched B (adjs) regs

  auto loadA = [&](int kc) {
#pragma unroll
    for (int i = 0; i < 3; ++i) {
      int unit = i * 512 + t;
      int row = unit >> 4, u = unit & 15;
      pa[i] = *(const uint2*)(Gd + (size_t)row * NK + kc * KC + u * 4);
    }
  };
  auto loadB = [&](int kc) {
#pragma unroll
    for (int i = 0; i < 4; ++i) {
      int row = i * 32 + brow;
      pb[i] = *(const float4*)(Adj + (size_t)(c0 + row) * NK + kc * KC + col4 * 4);
    }
  };

  loadA(0);
  loadB(0);

  for (int kc = 0; kc < NK / KC; ++kc) {
    // write prefetched regs -> LDS (reg use = implicit per-wave vmcnt wait)
#pragma unroll
    for (int i = 0; i < 3; ++i) {
      int unit = i * 512 + t;
      int row = unit >> 4, u = unit & 15;
      *(uint2*)(&S.p1.lA[row * LSTR + u * 4]) = pa[i];
    }
    float cs0 = 0, cs1 = 0, cs2 = 0, cs3 = 0;
#pragma unroll
    for (int i = 0; i < 4; ++i) {
      int row = i * 32 + brow;
      float4 v = pb[i];
      cs0 += v.x; cs1 += v.y; cs2 += v.z; cs3 += v.w;
      half4v hv = {(_Float16)v.x, (_Float16)v.y, (_Float16)v.z, (_Float16)v.w};
      *(half4v*)(&S.p1.lB[row * LSTR + col4 * 4]) = hv;
    }
    S.p1.degp[0][col4][brow] = cs0;
    S.p1.degp[1][col4][brow] = cs1;
    S.p1.degp[2][col4][brow] = cs2;
    S.p1.degp[3][col4][brow] = cs3;
    // issue next chunk's loads; they stay in flight across both barriers + MFMA
    if (kc < NK / KC - 1) {
      loadA(kc + 1);
      loadB(kc + 1);
    }
    FENCE_BARRIER();
    if (t < 64) {
      int cg = t >> 2, ci = t & 3;
      float sum = 0.f;
#pragma unroll
      for (int p = 0; p < 32; ++p) sum += S.p1.degp[ci][cg][p];
      int j = kc * KC + cg * 4 + ci;
      atomicAdd(deg + d * NL + (j & (NL - 1)), sum);
    }
#pragma unroll
    for (int ks = 0; ks < 2; ++ks) {
      int ko = ks * 32 + 8 * kg;
      half8 b0 = *(const half8*)(&S.p1.lB[(w * 16 + l16) * LSTR + ko]);
#pragma unroll
      for (int mf = 0; mf < 6; ++mf) {
        half8 a = *(const half8*)(&S.p1.lA[(mf * 16 + l16) * LSTR + ko]);
        acc[mf] = __builtin_amdgcn_mfma_f32_16x16x32_f16(a, b0, acc[mf], 0, 0, 0);
      }
    }
    FENCE_BARRIER();
  }

  // conv tile -> LDS (c-contiguous rows for part-2 A-fragments)
#pragma unroll
  for (int mf = 0; mf < 6; ++mf)
#pragma unroll
    for (int jj = 0; jj < 4; ++jj) {
      int m  = mf * 16 + kg * 4 + jj;
      S.p2.convT[m * CTS + w * 16 + l16] = (_Float16)acc[mf][jj];
    }

  // ---------------- part 2: aa2 partial [96 x 512] over 128 c ----------------
  float4 pc[8];             // prefetched A0 regs
  auto loadC = [&](int cc2) {
#pragma unroll
    for (int i = 0; i < 8; ++i) {
      int unit = i * 512 + t;
      int c  = unit >> 7;         // 0..31
      int l4 = unit & 127;
      pc[i] = *(const float4*)(Adj + (size_t)(2 * (c0 + cc2 * 32 + c)) * NL + l4 * 4);
    }
  };
  loadC(0);                 // in flight across the convT barrier
  FENCE_BARRIER();

  f32x4 acc2[6][4];
#pragma unroll
  for (int i = 0; i < 6; ++i)
#pragma unroll
    for (int q = 0; q < 4; ++q) acc2[i][q] = (f32x4)0.f;

  for (int cc2 = 0; cc2 < 4; ++cc2) {
#pragma unroll
    for (int i = 0; i < 8; ++i) {
      int unit = i * 512 + t;
      int c  = unit >> 7;
      int l4 = unit & 127;
      float4 v = pc[i];
      half4v hv = {(_Float16)v.x, (_Float16)v.y, (_Float16)v.z, (_Float16)v.w};
      *(half4v*)(&S.p2.lB2[c * BST2 + l4 * 4]) = hv;
    }
    if (cc2 < 3) loadC(cc2 + 1);
    FENCE_BARRIER();
    half8 bfr[4];
#pragma unroll
    for (int nf = 0; nf < 4; ++nf) {
      int lcol = w * 64 + nf * 16 + l16;
#pragma unroll
      for (int j = 0; j < 8; ++j)
        bfr[nf][j] = S.p2.lB2[(kg * 8 + j) * BST2 + lcol];
    }
#pragma unroll
    for (int mf = 0; mf < 6; ++mf) {
      half8 a = *(const half8*)(&S.p2.convT[(mf * 16 + l16) * CTS + cc2 * 32 + kg * 8]);
#pragma unroll
      for (int nf = 0; nf < 4; ++nf)
        acc2[mf][nf] = __builtin_amdgcn_mfma_f32_16x16x32_f16(a, bfr[nf], acc2[mf][nf], 0, 0, 0);
    }
    FENCE_BARRIER();
  }
  _Float16* outp = aa2p + (size_t)(ct * ND + d) * NR * NL;
#pragma unroll
  for (int mf = 0; mf < 6; ++mf)
#pragma unroll
    for (int nf = 0; nf < 4; ++nf)
#pragma unroll
      for (int jj = 0; jj < 4; ++jj) {
        int m = mf * 16 + kg * 4 + jj;
        int l = w * 64 + nf * 16 + l16;
        outp[(size_t)m * NL + l] = (_Float16)acc2[mf][nf][jj];
      }
}

// ---------- Reduce: one block per (d, r): sum 16 partials, /deg, max over l
__global__ __launch_bounds__(256) void k_reduce(const _Float16* __restrict__ aa2p,
                                                const float* __restrict__ deg,
                                                float* __restrict__ dmax) {
  __shared__ float wm[4];
  int r = blockIdx.x;         // 0..95
  int d = blockIdx.y;         // 0..15
  int t = threadIdx.x;
  int w = t >> 6, lane = t & 63;
  float best = -1e30f;
#pragma unroll
  for (int rep = 0; rep < 2; ++rep) {
    int l = t + rep * 256;
    float s = 0.f;
#pragma unroll
    for (int ct = 0; ct < NCT; ++ct)
      s += (float)aa2p[((size_t)(ct * ND + d) * NR + r) * NL + l];
    best = fmaxf(best, s / deg[d * NL + l]);
  }
#pragma unroll
  for (int off = 32; off >= 1; off >>= 1)
    best = fmaxf(best, __shfl_xor(best, off));
  if (lane == 0) wm[w] = best;
  __syncthreads();
  if (t == 0)
    dmax[d * NR + r] = fmaxf(fmaxf(wm[0], wm[1]), fmaxf(wm[2], wm[3]));
}

// ---------- Out: 128 scores = dot(dmax row, lin_w) -> sigmoid
__global__ __launch_bounds__(128) void k_out(const float* __restrict__ dmax,
                                             const float* __restrict__ lin_w,
                                             float* __restrict__ out) {
  int t = threadIdx.x;        // 0..127: d = t>>3, b = t&7
  int d = t >> 3, b = t & 7;
  float s = 0.f;
#pragma unroll
  for (int f = 0; f < NF; ++f)
    s += dmax[d * NR + b * NF + f] * lin_w[f];
  out[d * NB + b] = 1.f / (1.f + expf(-s));
}

extern "C" void kernel_launch(void* const* d_in, const int* in_sizes, int n_in,
                              void* d_out, int out_size, void* d_ws, size_t ws_size,
                              hipStream_t stream) {
  const float* aa     = (const float*)d_in[0];
  const float* adjs   = (const float*)d_in[1];
  const float* conv_w = (const float*)d_in[2];
  const float* lin_w  = (const float*)d_in[3];
  float* out = (float*)d_out;

  char* ws = (char*)d_ws;
  _Float16* G    = (_Float16*)ws;                       // 3,145,728 B
  _Float16* aa2p = (_Float16*)(ws + 3145728);           // 16 fp16 partials: 25,165,824 B
  float*    deg  = (float*)(ws + 3145728 + 25165824);   // 32 KB
  float*    dmax = (float*)(ws + 3145728 + 25165824 + 32768); // 6 KB

  hipMemsetAsync(deg, 0, ND * NL * sizeof(float), stream);

  k_g<<<dim3((ND * NR * NK) / 256), 256, 0, stream>>>(aa, conv_w, G);
  k_fused<<<dim3(256), 512, 0, stream>>>(adjs, G, aa2p, deg);
  k_reduce<<<dim3(NR, ND), 256, 0, stream>>>(aa2p, deg, dmax);
  k_out<<<dim3(1), 128, 0, stream>>>(dmax, lin_w, out);
}